// Round 14
// baseline (94.678 us; speedup 1.0000x reference)
//
#include <hip/hip_runtime.h>

#define BATCH 4
#define NPTS 8192
#define DIM 128
#define TOTAL_ROWS (BATCH * NPTS)   // 32768
#define SLICES 16                   // m-slices per batch
#define SLICE_W 512                 // cols per slice
#define ITERS 32                    // 16-col tiles per slice
#define TILES_PER_B 512             // NPTS/16
#define TILE_B 2048                 // bytes per packed fp8 16-col tile

typedef __attribute__((ext_vector_type(8))) int   i32x8;
typedef __attribute__((ext_vector_type(4))) float f32x4;

// monotonic encoding of float for unsigned atomicMin (handles negatives)
__device__ __forceinline__ unsigned encf(float f) {
  unsigned b = __float_as_uint(f);
  return (b & 0x80000000u) ? ~b : (b | 0x80000000u);
}
__device__ __forceinline__ float decf(unsigned u) {
  unsigned b = (u & 0x80000000u) ? (u ^ 0x80000000u) : ~u;
  return __uint_as_float(b);
}

// pack 8 floats -> 8 fp8(e4m3) bytes in 2 dwords
__device__ __forceinline__ void pk8(const float4& x, const float4& y,
                                    unsigned& lo, unsigned& hi) {
  lo = __builtin_amdgcn_cvt_pk_fp8_f32(x.x, x.y, 0, 0);
  lo = __builtin_amdgcn_cvt_pk_fp8_f32(x.z, x.w, lo, 1);
  hi = __builtin_amdgcn_cvt_pk_fp8_f32(y.x, y.y, 0, 0);
  hi = __builtin_amdgcn_cvt_pk_fp8_f32(y.z, y.w, hi, 1);
}

// ---- pack f_ into fp8 MFMA-fragment order + row norms gn2 ----
__global__ void pack_b_kernel(const float* __restrict__ in,
                              unsigned char* __restrict__ pk,
                              float* __restrict__ gn2) {
  __shared__ float sred[16][17];
  int tl  = threadIdx.x;               // 0..255
  int fl  = tl >> 2;                   // fragment lane 0..63
  int p   = tl & 3;                    // 8-byte group within lane's 32
  int col = fl & 15, kch = fl >> 4;
  int tile = blockIdx.x;               // b*512 + mtg
  int b = tile >> 9, mtg = tile & 511;
  const float* src = in + (size_t)(b * NPTS + mtg * 16 + col) * DIM + kch * 32 + p * 8;
  float4 x = ((const float4*)src)[0], y = ((const float4*)src)[1];
  unsigned lo, hi;
  pk8(x, y, lo, hi);
  *(uint2*)(pk + (size_t)tile * TILE_B + (p >> 1) * 1024 + fl * 16 + (p & 1) * 8)
      = make_uint2(lo, hi);
  float s = 0.f;
  s = fmaf(x.x, x.x, s); s = fmaf(x.y, x.y, s);
  s = fmaf(x.z, x.z, s); s = fmaf(x.w, x.w, s);
  s = fmaf(y.x, y.x, s); s = fmaf(y.y, y.y, s);
  s = fmaf(y.z, y.z, s); s = fmaf(y.w, y.w, s);
  sred[col][kch * 4 + p] = s;
  __syncthreads();
  if (tl < 16) {
    float t = 0.f;
    #pragma unroll
    for (int j = 0; j < 16; ++j) t += sred[tl][j];
    gn2[tile * 16 + tl] = t;
  }
}

// ---- main: per wave, 64 f-rows (A in fp8 regs) x 512-col slice ----
// grid 2048 = 8 blocks/CU demand, ~5-6 resident at 76 VGPR -> 2x occupancy vs R13
__global__ __launch_bounds__(256, 3)
void chamfer_mfma_kernel(const float* __restrict__ f,
                         const unsigned char* __restrict__ pk,
                         const float* __restrict__ gn2,
                         unsigned int* __restrict__ rowmin,
                         unsigned int* __restrict__ colmin) {
  const int lane = threadIdx.x & 63;
  const int l15  = lane & 15;
  const int q    = lane >> 4;                       // 0..3
  const int widx = threadIdx.x >> 6;                // 0..3

  // XCD-aware: 8 (b,slice) combos per XCD, 32 row-groups each
  const int bid   = blockIdx.x;                     // 0..2047
  const int combo = (bid & 7) * 8 + ((bid >> 3) & 7);  // 0..63
  const int b     = combo >> 4;
  const int slice = combo & 15;
  const int rgrp  = bid >> 6;                       // 0..31
  const int r0    = rgrp * 256 + widx * 64;
  const int bN    = b * NPTS;
  const int tile0 = b * TILES_PER_B + slice * ITERS;

  // block-level column-max accumulator of raw acc0; gn2 added at merge
  __shared__ unsigned cl[SLICE_W];
  for (int k = threadIdx.x; k < SLICE_W; k += 256)
    cl[k] = 0xFFFFFFFFu;
  __syncthreads();

  // ---- A fragments (4 tiles, fp8, K=128) + C-seeds h = -fn2/2 ----
  i32x8 af[4];
  f32x4 h[4];
  const float* fb = f + (size_t)bN * DIM;
  #pragma unroll
  for (int t = 0; t < 4; ++t) {
    const float* frow = fb + (size_t)(r0 + t * 16 + l15) * DIM + q * 32;
    float s = 0.f;
    i32x8 v;
    #pragma unroll
    for (int d8 = 0; d8 < 4; ++d8) {
      float4 x = ((const float4*)frow)[2 * d8];
      float4 y = ((const float4*)frow)[2 * d8 + 1];
      unsigned lo, hi;
      pk8(x, y, lo, hi);
      v[2 * d8] = (int)lo; v[2 * d8 + 1] = (int)hi;
      s = fmaf(x.x, x.x, s); s = fmaf(x.y, x.y, s);
      s = fmaf(x.z, x.z, s); s = fmaf(x.w, x.w, s);
      s = fmaf(y.x, y.x, s); s = fmaf(y.y, y.y, s);
      s = fmaf(y.z, y.z, s); s = fmaf(y.w, y.w, s);
    }
    af[t] = v;
    s += __shfl_xor(s, 16); s += __shfl_xor(s, 32);   // lane holds fn2 of row (l&15)
    #pragma unroll
    for (int i = 0; i < 4; ++i) h[t][i] = -0.5f * __shfl(s, (q << 2) + i);
  }

  float rowmax[4][4];
  #pragma unroll
  for (int t = 0; t < 4; ++t)
    #pragma unroll
    for (int i = 0; i < 4; ++i) rowmax[t][i] = -3.4e38f;

  // packed fragment base for this wave's lane
  const unsigned char* pkw = pk + (size_t)tile0 * TILE_B + lane * 16;
  const float*         gnb = gn2 + bN + slice * SLICE_W;

  auto loadB = [&](int mt, i32x8& bf, float& gv) {
    const unsigned char* base = pkw + (size_t)mt * TILE_B;
    uint4 u0 = *(const uint4*)base;
    uint4 u1 = *(const uint4*)(base + 1024);
    bf[0] = (int)u0.x; bf[1] = (int)u0.y; bf[2] = (int)u0.z; bf[3] = (int)u0.w;
    bf[4] = (int)u1.x; bf[5] = (int)u1.y; bf[6] = (int)u1.z; bf[7] = (int)u1.w;
    gv = gnb[mt * 16 + l15];
  };

  auto compute = [&](const i32x8& bf, float gv, int mt) {
    // C-operand seeding: acc0 = dot - fn2[r]/2  (no per-iter seed VALU)
    f32x4 acc[4];
    #pragma unroll
    for (int t = 0; t < 4; ++t)
      acc[t] = __builtin_amdgcn_mfma_scale_f32_16x16x128_f8f6f4(
          af[t], bf, h[t], 0, 0, 0, 0x7f7f7f7f, 0, 0x7f7f7f7f);

    // row side: rowmax tracks max(acc0 - gn2[c]/2) = -dis/2
    const float g2 = -0.5f * gv;
    #pragma unroll
    for (int t = 0; t < 4; ++t)
      #pragma unroll
      for (int i = 0; i < 4; ++i)
        rowmax[t][i] = fmaxf(rowmax[t][i], acc[t][i] + g2);

    // col side: cmax over the 16 raw acc0 (max3-fused tree: 8 ops)
    float m0 = fmaxf(fmaxf(acc[0][0], acc[0][1]), acc[0][2]);
    float m1 = fmaxf(fmaxf(acc[0][3], acc[1][0]), acc[1][1]);
    float m2 = fmaxf(fmaxf(acc[1][2], acc[1][3]), acc[2][0]);
    float m3 = fmaxf(fmaxf(acc[2][1], acc[2][2]), acc[2][3]);
    float m4 = fmaxf(fmaxf(acc[3][0], acc[3][1]), acc[3][2]);
    float n0 = fmaxf(fmaxf(m0, m1), m2);
    float n1 = fmaxf(fmaxf(m3, m4), acc[3][3]);
    float cmax = fmaxf(n0, n1);
    // fire-and-forget LDS atomic (4-way same-address per col); gn2 deferred
    atomicMin(&cl[mt * 16 + l15], encf(-2.f * cmax));
  };

  // 4-deep pipeline, named buffers, compute-then-reload rotation (distance 3)
  i32x8 b0, b1, b2, b3;
  float g0, g1, g2v, g3;
  loadB(0, b0, g0); loadB(1, b1, g1); loadB(2, b2, g2v); loadB(3, b3, g3);
  for (int mt = 0; mt < ITERS; mt += 4) {
    compute(b0, g0, mt);      loadB((mt + 4) & (ITERS - 1), b0, g0);
    compute(b1, g1, mt + 1);  loadB((mt + 5) & (ITERS - 1), b1, g1);
    compute(b2, g2v, mt + 2); loadB((mt + 6) & (ITERS - 1), b2, g2v);
    compute(b3, g3, mt + 3);  loadB((mt + 7) & (ITERS - 1), b3, g3);
  }

  // finalize row mins: reduce MAX over the 16 column-lanes, dis = -2*max
  #pragma unroll
  for (int t = 0; t < 4; ++t)
    #pragma unroll
    for (int i = 0; i < 4; ++i) {
      float v = rowmax[t][i];
      v = fmaxf(v, __shfl_xor(v, 1));
      v = fmaxf(v, __shfl_xor(v, 2));
      v = fmaxf(v, __shfl_xor(v, 4));
      v = fmaxf(v, __shfl_xor(v, 8));
      if (l15 == 0)
        atomicMin(&rowmin[bN + r0 + t * 16 + q * 4 + i], encf(-2.f * v));
    }

  // merge block col maxes into global: dis = decoded + gn2[col]
  __syncthreads();
  for (int c = threadIdx.x; c < SLICE_W; c += 256) {
    float d = decf(cl[c]) + gnb[c];
    atomicMin(&colmin[bN + slice * SLICE_W + c], encf(d));
  }
}

// ---- reduction stage 1: 128 blocks x 256 thr ----
__global__ void reduce1_kernel(const unsigned int* __restrict__ rowmin,
                               const unsigned int* __restrict__ colmin,
                               float* __restrict__ partial) {
  __shared__ float sbuf[4];
  int i = blockIdx.x * 256 + threadIdx.x;
  float s = decf(rowmin[i]) + decf(colmin[i]);
  #pragma unroll
  for (int o = 32; o >= 1; o >>= 1) s += __shfl_xor(s, o);
  if ((threadIdx.x & 63) == 0) sbuf[threadIdx.x >> 6] = s;
  __syncthreads();
  if (threadIdx.x == 0)
    partial[blockIdx.x] = sbuf[0] + sbuf[1] + sbuf[2] + sbuf[3];
}

// ---- reduction stage 2: 1 block, 64 thr ----
__global__ void reduce2_kernel(const float* __restrict__ partial,
                               float* __restrict__ out) {
  float s = partial[threadIdx.x] + partial[threadIdx.x + 64];
  #pragma unroll
  for (int o = 32; o >= 1; o >>= 1) s += __shfl_xor(s, o);
  if (threadIdx.x == 0) out[0] = s / (float)TOTAL_ROWS;
}

extern "C" void kernel_launch(void* const* d_in, const int* in_sizes, int n_in,
                              void* d_out, int out_size, void* d_ws, size_t ws_size,
                              hipStream_t stream) {
  (void)in_sizes; (void)n_in; (void)out_size; (void)ws_size;
  const float* f  = (const float*)d_in[0];
  const float* f_ = (const float*)d_in[1];

  char* ws = (char*)d_ws;
  unsigned char* pk = (unsigned char*)ws;                          // 4 MiB packed fp8 f_
  float* gn2 = (float*)(ws + 8u * 1024u * 1024u);                  // 128 KiB
  unsigned int* rowmin = (unsigned int*)(gn2 + TOTAL_ROWS);        // 128 KiB
  unsigned int* colmin = rowmin + TOTAL_ROWS;                      // 128 KiB
  float* partial = (float*)(colmin + TOTAL_ROWS);                  // 512 B

  pack_b_kernel<<<2048, 256, 0, stream>>>(f_, pk, gn2);
  hipMemsetAsync(rowmin, 0xFF, (size_t)TOTAL_ROWS * 4, stream);
  hipMemsetAsync(colmin, 0xFF, (size_t)TOTAL_ROWS * 4, stream);
  chamfer_mfma_kernel<<<2048, 256, 0, stream>>>(f, pk, gn2, rowmin, colmin);
  reduce1_kernel<<<128, 256, 0, stream>>>(rowmin, colmin, partial);
  reduce2_kernel<<<1, 64, 0, stream>>>(partial, (float*)d_out);
}

// Round 15
// 75.206 us; speedup vs baseline: 1.2589x; 1.2589x over previous
//
#include <hip/hip_runtime.h>

#define BATCH 4
#define NPTS 8192
#define DIM 128
#define TOTAL_ROWS (BATCH * NPTS)   // 32768
#define SLICES 8                    // m-slices per batch
#define SLICE_W 1024                // cols per slice
#define ITERS 64                    // 16-col tiles per slice
#define TILES_PER_B 512             // NPTS/16
#define TILE_B 2048                 // bytes per packed fp8 16-col tile

typedef __attribute__((ext_vector_type(8))) int   i32x8;
typedef __attribute__((ext_vector_type(4))) float f32x4;

// monotonic encoding of float for unsigned atomicMin (handles negatives)
__device__ __forceinline__ unsigned encf(float f) {
  unsigned b = __float_as_uint(f);
  return (b & 0x80000000u) ? ~b : (b | 0x80000000u);
}
__device__ __forceinline__ float decf(unsigned u) {
  unsigned b = (u & 0x80000000u) ? (u ^ 0x80000000u) : ~u;
  return __uint_as_float(b);
}

// pack 8 floats -> 8 fp8(e4m3) bytes in 2 dwords
__device__ __forceinline__ void pk8(const float4& x, const float4& y,
                                    unsigned& lo, unsigned& hi) {
  lo = __builtin_amdgcn_cvt_pk_fp8_f32(x.x, x.y, 0, 0);
  lo = __builtin_amdgcn_cvt_pk_fp8_f32(x.z, x.w, lo, 1);
  hi = __builtin_amdgcn_cvt_pk_fp8_f32(y.x, y.y, 0, 0);
  hi = __builtin_amdgcn_cvt_pk_fp8_f32(y.z, y.w, hi, 1);
}

// ---- pack f_ into fp8 MFMA-fragment order + row norms gn2 ----
__global__ void pack_b_kernel(const float* __restrict__ in,
                              unsigned char* __restrict__ pk,
                              float* __restrict__ gn2) {
  __shared__ float sred[16][17];
  int tl  = threadIdx.x;               // 0..255
  int fl  = tl >> 2;                   // fragment lane 0..63
  int p   = tl & 3;                    // 8-byte group within lane's 32
  int col = fl & 15, kch = fl >> 4;
  int tile = blockIdx.x;               // b*512 + mtg
  int b = tile >> 9, mtg = tile & 511;
  const float* src = in + (size_t)(b * NPTS + mtg * 16 + col) * DIM + kch * 32 + p * 8;
  float4 x = ((const float4*)src)[0], y = ((const float4*)src)[1];
  unsigned lo, hi;
  pk8(x, y, lo, hi);
  *(uint2*)(pk + (size_t)tile * TILE_B + (p >> 1) * 1024 + fl * 16 + (p & 1) * 8)
      = make_uint2(lo, hi);
  float s = 0.f;
  s = fmaf(x.x, x.x, s); s = fmaf(x.y, x.y, s);
  s = fmaf(x.z, x.z, s); s = fmaf(x.w, x.w, s);
  s = fmaf(y.x, y.x, s); s = fmaf(y.y, y.y, s);
  s = fmaf(y.z, y.z, s); s = fmaf(y.w, y.w, s);
  sred[col][kch * 4 + p] = s;
  __syncthreads();
  if (tl < 16) {
    float t = 0.f;
    #pragma unroll
    for (int j = 0; j < 16; ++j) t += sred[tl][j];
    gn2[tile * 16 + tl] = t;
  }
}

// ---- main: per wave, 64 f-rows (A in fp8 regs) x 1024-col slice ----
// fp8 K=128 MFMA, C-seeding, deferred gn2, max3 tree, 4-deep B prefetch,
// + acc double-pipeline: MFMAs of tile n+1 issue BEFORE epilogue of tile n
__global__ __launch_bounds__(256, 3)
void chamfer_mfma_kernel(const float* __restrict__ f,
                         const unsigned char* __restrict__ pk,
                         const float* __restrict__ gn2,
                         unsigned int* __restrict__ rowmin,
                         unsigned int* __restrict__ colmin) {
  const int lane = threadIdx.x & 63;
  const int l15  = lane & 15;
  const int q    = lane >> 4;                       // 0..3
  const int widx = threadIdx.x >> 6;                // 0..3

  // XCD-aware: 4 (b,slice) combos per XCD, 32 row-groups each
  const int bid   = blockIdx.x;                     // 0..1023
  const int combo = (bid & 7) * 4 + ((bid >> 3) & 3);  // 0..31
  const int b     = combo >> 3;
  const int slice = combo & 7;
  const int rgrp  = bid >> 5;                       // 0..31
  const int r0    = rgrp * 256 + widx * 64;
  const int bN    = b * NPTS;
  const int tile0 = b * TILES_PER_B + slice * ITERS;

  // block-level column-max accumulator of raw acc0; gn2 added at merge
  __shared__ unsigned cl[SLICE_W];
  #pragma unroll
  for (int k = 0; k < SLICE_W / 256; ++k)
    cl[threadIdx.x + k * 256] = 0xFFFFFFFFu;
  __syncthreads();

  // ---- A fragments (4 tiles, fp8, K=128) + C-seeds h = -fn2/2 ----
  i32x8 af[4];
  f32x4 h[4];
  const float* fb = f + (size_t)bN * DIM;
  #pragma unroll
  for (int t = 0; t < 4; ++t) {
    const float* frow = fb + (size_t)(r0 + t * 16 + l15) * DIM + q * 32;
    float s = 0.f;
    i32x8 v;
    #pragma unroll
    for (int d8 = 0; d8 < 4; ++d8) {
      float4 x = ((const float4*)frow)[2 * d8];
      float4 y = ((const float4*)frow)[2 * d8 + 1];
      unsigned lo, hi;
      pk8(x, y, lo, hi);
      v[2 * d8] = (int)lo; v[2 * d8 + 1] = (int)hi;
      s = fmaf(x.x, x.x, s); s = fmaf(x.y, x.y, s);
      s = fmaf(x.z, x.z, s); s = fmaf(x.w, x.w, s);
      s = fmaf(y.x, y.x, s); s = fmaf(y.y, y.y, s);
      s = fmaf(y.z, y.z, s); s = fmaf(y.w, y.w, s);
    }
    af[t] = v;
    s += __shfl_xor(s, 16); s += __shfl_xor(s, 32);   // lane holds fn2 of row (l&15)
    #pragma unroll
    for (int i = 0; i < 4; ++i) h[t][i] = -0.5f * __shfl(s, (q << 2) + i);
  }

  float rowmax[4][4];
  #pragma unroll
  for (int t = 0; t < 4; ++t)
    #pragma unroll
    for (int i = 0; i < 4; ++i) rowmax[t][i] = -3.4e38f;

  // packed fragment base for this wave's lane
  const unsigned char* pkw = pk + (size_t)tile0 * TILE_B + lane * 16;
  const float*         gnb = gn2 + bN + slice * SLICE_W;

  auto loadB = [&](int mt, i32x8& bf, float& gv) {
    const unsigned char* base = pkw + (size_t)mt * TILE_B;
    uint4 u0 = *(const uint4*)base;
    uint4 u1 = *(const uint4*)(base + 1024);
    bf[0] = (int)u0.x; bf[1] = (int)u0.y; bf[2] = (int)u0.z; bf[3] = (int)u0.w;
    bf[4] = (int)u1.x; bf[5] = (int)u1.y; bf[6] = (int)u1.z; bf[7] = (int)u1.w;
    gv = gnb[mt * 16 + l15];
  };

  // issue the 4 MFMAs for one tile (C-operand seeded with -fn2/2)
  auto mfma4 = [&](const i32x8& bf, f32x4 acc[4]) {
    #pragma unroll
    for (int t = 0; t < 4; ++t)
      acc[t] = __builtin_amdgcn_mfma_scale_f32_16x16x128_f8f6f4(
          af[t], bf, h[t], 0, 0, 0, 0x7f7f7f7f, 0, 0x7f7f7f7f);
  };

  // epilogue for a finished tile
  auto epi = [&](const f32x4 acc[4], float gv, int mt) {
    const float g2 = -0.5f * gv;
    #pragma unroll
    for (int t = 0; t < 4; ++t)
      #pragma unroll
      for (int i = 0; i < 4; ++i)
        rowmax[t][i] = fmaxf(rowmax[t][i], acc[t][i] + g2);
    float m0 = fmaxf(fmaxf(acc[0][0], acc[0][1]), acc[0][2]);
    float m1 = fmaxf(fmaxf(acc[0][3], acc[1][0]), acc[1][1]);
    float m2 = fmaxf(fmaxf(acc[1][2], acc[1][3]), acc[2][0]);
    float m3 = fmaxf(fmaxf(acc[2][1], acc[2][2]), acc[2][3]);
    float m4 = fmaxf(fmaxf(acc[3][0], acc[3][1]), acc[3][2]);
    float n0 = fmaxf(fmaxf(m0, m1), m2);
    float n1 = fmaxf(fmaxf(m3, m4), acc[3][3]);
    float cmax = fmaxf(n0, n1);
    atomicMin(&cl[mt * 16 + l15], encf(-2.f * cmax));
  };

  // 4-deep B prefetch + 2-deep acc pipeline.
  // Body: issue MFMAs(tile n+1) -> epilogue(tile n) -> reload B slot.
  i32x8 b0, b1, b2, b3;
  float g0, g1, g2v, g3;
  loadB(0, b0, g0); loadB(1, b1, g1); loadB(2, b2, g2v); loadB(3, b3, g3);
  f32x4 accA[4], accB[4];
  mfma4(b0, accA);                                  // tile 0 in flight
  for (int mt = 0; mt < ITERS; mt += 4) {
    mfma4(b1, accB);                                // tile mt+1 in flight
    epi(accA, g0, mt);                              // finish tile mt
    loadB((mt + 4) & (ITERS - 1), b0, g0);
    mfma4(b2, accA);                                // tile mt+2
    epi(accB, g1, mt + 1);
    loadB((mt + 5) & (ITERS - 1), b1, g1);
    mfma4(b3, accB);                                // tile mt+3
    epi(accA, g2v, mt + 2);
    loadB((mt + 6) & (ITERS - 1), b2, g2v);
    mfma4(b0, accA);                                // tile mt+4 (wraps on last)
    epi(accB, g3, mt + 3);
    loadB((mt + 7) & (ITERS - 1), b3, g3);
  }
  // (the final wrapped mfma4(b0,accA) result is never read - 1.5% waste)

  // finalize row mins: reduce MAX over the 16 column-lanes, dis = -2*max
  #pragma unroll
  for (int t = 0; t < 4; ++t)
    #pragma unroll
    for (int i = 0; i < 4; ++i) {
      float v = rowmax[t][i];
      v = fmaxf(v, __shfl_xor(v, 1));
      v = fmaxf(v, __shfl_xor(v, 2));
      v = fmaxf(v, __shfl_xor(v, 4));
      v = fmaxf(v, __shfl_xor(v, 8));
      if (l15 == 0)
        atomicMin(&rowmin[bN + r0 + t * 16 + q * 4 + i], encf(-2.f * v));
    }

  // merge block col maxes into global: dis = decoded + gn2[col]
  __syncthreads();
  #pragma unroll
  for (int k = 0; k < SLICE_W / 256; ++k) {
    int c = threadIdx.x + k * 256;
    float d = decf(cl[c]) + gnb[c];
    atomicMin(&colmin[bN + slice * SLICE_W + c], encf(d));
  }
}

// ---- reduction stage 1: 128 blocks x 256 thr ----
__global__ void reduce1_kernel(const unsigned int* __restrict__ rowmin,
                               const unsigned int* __restrict__ colmin,
                               float* __restrict__ partial) {
  __shared__ float sbuf[4];
  int i = blockIdx.x * 256 + threadIdx.x;
  float s = decf(rowmin[i]) + decf(colmin[i]);
  #pragma unroll
  for (int o = 32; o >= 1; o >>= 1) s += __shfl_xor(s, o);
  if ((threadIdx.x & 63) == 0) sbuf[threadIdx.x >> 6] = s;
  __syncthreads();
  if (threadIdx.x == 0)
    partial[blockIdx.x] = sbuf[0] + sbuf[1] + sbuf[2] + sbuf[3];
}

// ---- reduction stage 2: 1 block, 64 thr ----
__global__ void reduce2_kernel(const float* __restrict__ partial,
                               float* __restrict__ out) {
  float s = partial[threadIdx.x] + partial[threadIdx.x + 64];
  #pragma unroll
  for (int o = 32; o >= 1; o >>= 1) s += __shfl_xor(s, o);
  if (threadIdx.x == 0) out[0] = s / (float)TOTAL_ROWS;
}

extern "C" void kernel_launch(void* const* d_in, const int* in_sizes, int n_in,
                              void* d_out, int out_size, void* d_ws, size_t ws_size,
                              hipStream_t stream) {
  (void)in_sizes; (void)n_in; (void)out_size; (void)ws_size;
  const float* f  = (const float*)d_in[0];
  const float* f_ = (const float*)d_in[1];

  char* ws = (char*)d_ws;
  unsigned char* pk = (unsigned char*)ws;                          // 4 MiB packed fp8 f_
  float* gn2 = (float*)(ws + 8u * 1024u * 1024u);                  // 128 KiB
  unsigned int* rowmin = (unsigned int*)(gn2 + TOTAL_ROWS);        // 128 KiB
  unsigned int* colmin = rowmin + TOTAL_ROWS;                      // 128 KiB
  float* partial = (float*)(colmin + TOTAL_ROWS);                  // 512 B

  pack_b_kernel<<<2048, 256, 0, stream>>>(f_, pk, gn2);
  hipMemsetAsync(rowmin, 0xFF, (size_t)TOTAL_ROWS * 4, stream);
  hipMemsetAsync(colmin, 0xFF, (size_t)TOTAL_ROWS * 4, stream);
  chamfer_mfma_kernel<<<1024, 256, 0, stream>>>(f, pk, gn2, rowmin, colmin);
  reduce1_kernel<<<128, 256, 0, stream>>>(rowmin, colmin, partial);
  reduce2_kernel<<<1, 64, 0, stream>>>(partial, (float*)d_out);
}

// Round 16
// 74.835 us; speedup vs baseline: 1.2652x; 1.0050x over previous
//
#include <hip/hip_runtime.h>

#define BATCH 4
#define NPTS 8192
#define DIM 128
#define TOTAL_ROWS (BATCH * NPTS)   // 32768
#define SLICES 8                    // m-slices per batch
#define SLICE_W 1024                // cols per slice
#define ITERS 64                    // 16-col tiles per slice
#define TILES_PER_B 512             // NPTS/16
#define TILE_B 2048                 // bytes per packed fp8 16-col tile

typedef __attribute__((ext_vector_type(8))) int   i32x8;
typedef __attribute__((ext_vector_type(4))) float f32x4;

// monotonic encoding of float for unsigned atomicMin (handles negatives)
__device__ __forceinline__ unsigned encf(float f) {
  unsigned b = __float_as_uint(f);
  return (b & 0x80000000u) ? ~b : (b | 0x80000000u);
}
__device__ __forceinline__ float decf(unsigned u) {
  unsigned b = (u & 0x80000000u) ? (u ^ 0x80000000u) : ~u;
  return __uint_as_float(b);
}

// pack 8 floats -> 8 fp8(e4m3) bytes in 2 dwords
__device__ __forceinline__ void pk8(const float4& x, const float4& y,
                                    unsigned& lo, unsigned& hi) {
  lo = __builtin_amdgcn_cvt_pk_fp8_f32(x.x, x.y, 0, 0);
  lo = __builtin_amdgcn_cvt_pk_fp8_f32(x.z, x.w, lo, 1);
  hi = __builtin_amdgcn_cvt_pk_fp8_f32(y.x, y.y, 0, 0);
  hi = __builtin_amdgcn_cvt_pk_fp8_f32(y.z, y.w, hi, 1);
}

// ---- pack f_ into fp8 MFMA-fragment order + row norms gn2 ----
__global__ void pack_b_kernel(const float* __restrict__ in,
                              unsigned char* __restrict__ pk,
                              float* __restrict__ gn2) {
  __shared__ float sred[16][17];
  int tl  = threadIdx.x;               // 0..255
  int fl  = tl >> 2;                   // fragment lane 0..63
  int p   = tl & 3;                    // 8-byte group within lane's 32
  int col = fl & 15, kch = fl >> 4;
  int tile = blockIdx.x;               // b*512 + mtg
  int b = tile >> 9, mtg = tile & 511;
  const float* src = in + (size_t)(b * NPTS + mtg * 16 + col) * DIM + kch * 32 + p * 8;
  float4 x = ((const float4*)src)[0], y = ((const float4*)src)[1];
  unsigned lo, hi;
  pk8(x, y, lo, hi);
  *(uint2*)(pk + (size_t)tile * TILE_B + (p >> 1) * 1024 + fl * 16 + (p & 1) * 8)
      = make_uint2(lo, hi);
  float s = 0.f;
  s = fmaf(x.x, x.x, s); s = fmaf(x.y, x.y, s);
  s = fmaf(x.z, x.z, s); s = fmaf(x.w, x.w, s);
  s = fmaf(y.x, y.x, s); s = fmaf(y.y, y.y, s);
  s = fmaf(y.z, y.z, s); s = fmaf(y.w, y.w, s);
  sred[col][kch * 4 + p] = s;
  __syncthreads();
  if (tl < 16) {
    float t = 0.f;
    #pragma unroll
    for (int j = 0; j < 16; ++j) t += sred[tl][j];
    gn2[tile * 16 + tl] = t;
  }
}

// ---- main: per wave, 64 f-rows (A in fp8 regs) x 1024-col slice ----
// fp8 K=128 MFMA, C-seeding, deferred gn2, max3 tree, 2-deep ping-pong.
// LB(256,4): lean footprint (~113 incl acc) fits 128 budget -> 4 waves/SIMD
__global__ __launch_bounds__(256, 4)
void chamfer_mfma_kernel(const float* __restrict__ f,
                         const unsigned char* __restrict__ pk,
                         const float* __restrict__ gn2,
                         unsigned int* __restrict__ rowmin,
                         unsigned int* __restrict__ colmin) {
  const int lane = threadIdx.x & 63;
  const int l15  = lane & 15;
  const int q    = lane >> 4;                       // 0..3
  const int widx = threadIdx.x >> 6;                // 0..3

  // XCD-aware: 4 (b,slice) combos per XCD, 32 row-groups each
  const int bid   = blockIdx.x;                     // 0..1023
  const int combo = (bid & 7) * 4 + ((bid >> 3) & 3);  // 0..31
  const int b     = combo >> 3;
  const int slice = combo & 7;
  const int rgrp  = bid >> 5;                       // 0..31
  const int r0    = rgrp * 256 + widx * 64;
  const int bN    = b * NPTS;
  const int tile0 = b * TILES_PER_B + slice * ITERS;

  // block-level column-max accumulator of raw acc0; gn2 added at merge
  __shared__ unsigned cl[SLICE_W];
  #pragma unroll
  for (int k = 0; k < SLICE_W / 256; ++k)
    cl[threadIdx.x + k * 256] = 0xFFFFFFFFu;
  __syncthreads();

  // ---- A fragments (4 tiles, fp8, K=128) + C-seeds h = -fn2/2 ----
  i32x8 af[4];
  f32x4 h[4];
  const float* fb = f + (size_t)bN * DIM;
  #pragma unroll
  for (int t = 0; t < 4; ++t) {
    const float* frow = fb + (size_t)(r0 + t * 16 + l15) * DIM + q * 32;
    float s = 0.f;
    i32x8 v;
    #pragma unroll
    for (int d8 = 0; d8 < 4; ++d8) {
      float4 x = ((const float4*)frow)[2 * d8];
      float4 y = ((const float4*)frow)[2 * d8 + 1];
      unsigned lo, hi;
      pk8(x, y, lo, hi);
      v[2 * d8] = (int)lo; v[2 * d8 + 1] = (int)hi;
      s = fmaf(x.x, x.x, s); s = fmaf(x.y, x.y, s);
      s = fmaf(x.z, x.z, s); s = fmaf(x.w, x.w, s);
      s = fmaf(y.x, y.x, s); s = fmaf(y.y, y.y, s);
      s = fmaf(y.z, y.z, s); s = fmaf(y.w, y.w, s);
    }
    af[t] = v;
    s += __shfl_xor(s, 16); s += __shfl_xor(s, 32);   // lane holds fn2 of row (l&15)
    #pragma unroll
    for (int i = 0; i < 4; ++i) h[t][i] = -0.5f * __shfl(s, (q << 2) + i);
  }

  float rowmax[4][4];
  #pragma unroll
  for (int t = 0; t < 4; ++t)
    #pragma unroll
    for (int i = 0; i < 4; ++i) rowmax[t][i] = -3.4e38f;

  // packed fragment base for this wave's lane
  const unsigned char* pkw = pk + (size_t)tile0 * TILE_B + lane * 16;
  const float*         gnb = gn2 + bN + slice * SLICE_W;

  auto loadB = [&](int mt, i32x8& bf, float& gv) {
    const unsigned char* base = pkw + (size_t)mt * TILE_B;
    uint4 u0 = *(const uint4*)base;
    uint4 u1 = *(const uint4*)(base + 1024);
    bf[0] = (int)u0.x; bf[1] = (int)u0.y; bf[2] = (int)u0.z; bf[3] = (int)u0.w;
    bf[4] = (int)u1.x; bf[5] = (int)u1.y; bf[6] = (int)u1.z; bf[7] = (int)u1.w;
    gv = gnb[mt * 16 + l15];
  };

  auto compute = [&](const i32x8& bf, float gv, int mt) {
    // C-operand seeding: acc0 = dot - fn2[r]/2  (no per-iter seed VALU)
    f32x4 acc[4];
    #pragma unroll
    for (int t = 0; t < 4; ++t)
      acc[t] = __builtin_amdgcn_mfma_scale_f32_16x16x128_f8f6f4(
          af[t], bf, h[t], 0, 0, 0, 0x7f7f7f7f, 0, 0x7f7f7f7f);

    // row side: rowmax tracks max(acc0 - gn2[c]/2) = -dis/2
    const float g2 = -0.5f * gv;
    #pragma unroll
    for (int t = 0; t < 4; ++t)
      #pragma unroll
      for (int i = 0; i < 4; ++i)
        rowmax[t][i] = fmaxf(rowmax[t][i], acc[t][i] + g2);

    // col side: cmax over the 16 raw acc0 (max3-fused tree: 8 ops)
    float m0 = fmaxf(fmaxf(acc[0][0], acc[0][1]), acc[0][2]);
    float m1 = fmaxf(fmaxf(acc[0][3], acc[1][0]), acc[1][1]);
    float m2 = fmaxf(fmaxf(acc[1][2], acc[1][3]), acc[2][0]);
    float m3 = fmaxf(fmaxf(acc[2][1], acc[2][2]), acc[2][3]);
    float m4 = fmaxf(fmaxf(acc[3][0], acc[3][1]), acc[3][2]);
    float n0 = fmaxf(fmaxf(m0, m1), m2);
    float n1 = fmaxf(fmaxf(m3, m4), acc[3][3]);
    float cmax = fmaxf(n0, n1);
    // fire-and-forget LDS atomic (4-way same-address per col); gn2 deferred
    atomicMin(&cl[mt * 16 + l15], encf(-2.f * cmax));
  };

  // 2-deep ping-pong (R10's lean register structure)
  i32x8 bA, bB;
  float gA, gB;
  loadB(0, bA, gA);
  for (int mt = 0; mt < ITERS; mt += 2) {
    loadB(mt + 1, bB, gB);
    compute(bA, gA, mt);
    loadB((mt + 2) & (ITERS - 1), bA, gA);
    compute(bB, gB, mt + 1);
  }

  // finalize row mins: reduce MAX over the 16 column-lanes, dis = -2*max
  #pragma unroll
  for (int t = 0; t < 4; ++t)
    #pragma unroll
    for (int i = 0; i < 4; ++i) {
      float v = rowmax[t][i];
      v = fmaxf(v, __shfl_xor(v, 1));
      v = fmaxf(v, __shfl_xor(v, 2));
      v = fmaxf(v, __shfl_xor(v, 4));
      v = fmaxf(v, __shfl_xor(v, 8));
      if (l15 == 0)
        atomicMin(&rowmin[bN + r0 + t * 16 + q * 4 + i], encf(-2.f * v));
    }

  // merge block col maxes into global: dis = decoded + gn2[col]
  __syncthreads();
  #pragma unroll
  for (int k = 0; k < SLICE_W / 256; ++k) {
    int c = threadIdx.x + k * 256;
    float d = decf(cl[c]) + gnb[c];
    atomicMin(&colmin[bN + slice * SLICE_W + c], encf(d));
  }
}

// ---- reduction stage 1: 128 blocks x 256 thr ----
__global__ void reduce1_kernel(const unsigned int* __restrict__ rowmin,
                               const unsigned int* __restrict__ colmin,
                               float* __restrict__ partial) {
  __shared__ float sbuf[4];
  int i = blockIdx.x * 256 + threadIdx.x;
  float s = decf(rowmin[i]) + decf(colmin[i]);
  #pragma unroll
  for (int o = 32; o >= 1; o >>= 1) s += __shfl_xor(s, o);
  if ((threadIdx.x & 63) == 0) sbuf[threadIdx.x >> 6] = s;
  __syncthreads();
  if (threadIdx.x == 0)
    partial[blockIdx.x] = sbuf[0] + sbuf[1] + sbuf[2] + sbuf[3];
}

// ---- reduction stage 2: 1 block, 64 thr ----
__global__ void reduce2_kernel(const float* __restrict__ partial,
                               float* __restrict__ out) {
  float s = partial[threadIdx.x] + partial[threadIdx.x + 64];
  #pragma unroll
  for (int o = 32; o >= 1; o >>= 1) s += __shfl_xor(s, o);
  if (threadIdx.x == 0) out[0] = s / (float)TOTAL_ROWS;
}

extern "C" void kernel_launch(void* const* d_in, const int* in_sizes, int n_in,
                              void* d_out, int out_size, void* d_ws, size_t ws_size,
                              hipStream_t stream) {
  (void)in_sizes; (void)n_in; (void)out_size; (void)ws_size;
  const float* f  = (const float*)d_in[0];
  const float* f_ = (const float*)d_in[1];

  char* ws = (char*)d_ws;
  unsigned char* pk = (unsigned char*)ws;                          // 4 MiB packed fp8 f_
  float* gn2 = (float*)(ws + 8u * 1024u * 1024u);                  // 128 KiB
  unsigned int* rowmin = (unsigned int*)(gn2 + TOTAL_ROWS);        // 128 KiB
  unsigned int* colmin = rowmin + TOTAL_ROWS;                      // 128 KiB
  float* partial = (float*)(colmin + TOTAL_ROWS);                  // 512 B

  pack_b_kernel<<<2048, 256, 0, stream>>>(f_, pk, gn2);
  hipMemsetAsync(rowmin, 0xFF, (size_t)TOTAL_ROWS * 4, stream);
  hipMemsetAsync(colmin, 0xFF, (size_t)TOTAL_ROWS * 4, stream);
  chamfer_mfma_kernel<<<1024, 256, 0, stream>>>(f, pk, gn2, rowmin, colmin);
  reduce1_kernel<<<128, 256, 0, stream>>>(rowmin, colmin, partial);
  reduce2_kernel<<<1, 64, 0, stream>>>(partial, (float*)d_out);
}

// Round 17
// 64.244 us; speedup vs baseline: 1.4737x; 1.1649x over previous
//
#include <hip/hip_runtime.h>

#define BATCH 4
#define NPTS 8192
#define DIM 128
#define TOTAL_ROWS (BATCH * NPTS)   // 32768
#define SLICES 8                    // m-slices per batch
#define SLICE_W 1024                // cols per slice
#define ITERS 64                    // 16-col tiles per slice
#define TILES_PER_B 512             // NPTS/16
#define TILE_B 2048                 // bytes per packed fp8 16-col tile

typedef __attribute__((ext_vector_type(8))) int   i32x8;
typedef __attribute__((ext_vector_type(4))) float f32x4;

// monotonic encoding of float for unsigned atomicMin (handles negatives)
__device__ __forceinline__ unsigned encf(float f) {
  unsigned b = __float_as_uint(f);
  return (b & 0x80000000u) ? ~b : (b | 0x80000000u);
}
__device__ __forceinline__ float decf(unsigned u) {
  unsigned b = (u & 0x80000000u) ? (u ^ 0x80000000u) : ~u;
  return __uint_as_float(b);
}

// pack 8 floats -> 8 fp8(e4m3) bytes in 2 dwords
__device__ __forceinline__ void pk8(const float4& x, const float4& y,
                                    unsigned& lo, unsigned& hi) {
  lo = __builtin_amdgcn_cvt_pk_fp8_f32(x.x, x.y, 0, 0);
  lo = __builtin_amdgcn_cvt_pk_fp8_f32(x.z, x.w, lo, 1);
  hi = __builtin_amdgcn_cvt_pk_fp8_f32(y.x, y.y, 0, 0);
  hi = __builtin_amdgcn_cvt_pk_fp8_f32(y.z, y.w, hi, 1);
}

// ---- pack a point set into fp8 MFMA-fragment order + row norms ----
// (A and B fragment layouts coincide for mfma_scale 16x16x128, so this
//  kernel is used for BOTH f and f_)
__global__ void pack_kernel(const float* __restrict__ in,
                            unsigned char* __restrict__ pk,
                            float* __restrict__ n2) {
  __shared__ float sred[16][17];
  int tl  = threadIdx.x;               // 0..255
  int fl  = tl >> 2;                   // fragment lane 0..63
  int p   = tl & 3;                    // 8-byte group within lane's 32
  int row = fl & 15, kch = fl >> 4;
  int tile = blockIdx.x;               // b*512 + mtg
  int b = tile >> 9, mtg = tile & 511;
  const float* src = in + (size_t)(b * NPTS + mtg * 16 + row) * DIM + kch * 32 + p * 8;
  float4 x = ((const float4*)src)[0], y = ((const float4*)src)[1];
  unsigned lo, hi;
  pk8(x, y, lo, hi);
  *(uint2*)(pk + (size_t)tile * TILE_B + (p >> 1) * 1024 + fl * 16 + (p & 1) * 8)
      = make_uint2(lo, hi);
  float s = 0.f;
  s = fmaf(x.x, x.x, s); s = fmaf(x.y, x.y, s);
  s = fmaf(x.z, x.z, s); s = fmaf(x.w, x.w, s);
  s = fmaf(y.x, y.x, s); s = fmaf(y.y, y.y, s);
  s = fmaf(y.z, y.z, s); s = fmaf(y.w, y.w, s);
  sred[row][kch * 4 + p] = s;
  __syncthreads();
  if (tl < 16) {
    float t = 0.f;
    #pragma unroll
    for (int j = 0; j < 16; ++j) t += sred[tl][j];
    n2[tile * 16 + tl] = t;
  }
}

// ---- main: per wave, 64 f-rows (packed fp8 A) x 1024-col slice ----
// fp8 K=128 MFMA, C-seeding, sequential-t with 2-acc ping-pong (8 acc regs),
// setprio around MFMA, 2-deep B ping-pong. LB(256,4).
__global__ __launch_bounds__(256, 4)
void chamfer_mfma_kernel(const unsigned char* __restrict__ pkA,
                         const unsigned char* __restrict__ pkB,
                         const float* __restrict__ fn2,
                         const float* __restrict__ gn2,
                         unsigned int* __restrict__ rowmin,
                         unsigned int* __restrict__ colmin) {
  const int lane = threadIdx.x & 63;
  const int l15  = lane & 15;
  const int q    = lane >> 4;                       // 0..3
  const int widx = threadIdx.x >> 6;                // 0..3

  // XCD-aware: 4 (b,slice) combos per XCD, 32 row-groups each
  const int bid   = blockIdx.x;                     // 0..1023
  const int combo = (bid & 7) * 4 + ((bid >> 3) & 3);  // 0..31
  const int b     = combo >> 3;
  const int slice = combo & 7;
  const int rgrp  = bid >> 5;                       // 0..31
  const int r0    = rgrp * 256 + widx * 64;
  const int bN    = b * NPTS;
  const int tile0 = b * TILES_PER_B + slice * ITERS;

  // block-level column-max accumulator of raw acc; gn2 added at merge
  __shared__ unsigned cl[SLICE_W];
  #pragma unroll
  for (int k = 0; k < SLICE_W / 256; ++k)
    cl[threadIdx.x + k * 256] = 0xFFFFFFFFu;
  __syncthreads();

  // ---- A fragments from packed pkA (8 coalesced dwordx4 loads) ----
  i32x8 af[4];
  const int atile0 = b * TILES_PER_B + (r0 >> 4);
  #pragma unroll
  for (int t = 0; t < 4; ++t) {
    const unsigned char* abase =
        pkA + (size_t)(atile0 + t) * TILE_B + lane * 16;
    uint4 u0 = *(const uint4*)abase;
    uint4 u1 = *(const uint4*)(abase + 1024);
    i32x8 v;
    v[0] = (int)u0.x; v[1] = (int)u0.y; v[2] = (int)u0.z; v[3] = (int)u0.w;
    v[4] = (int)u1.x; v[5] = (int)u1.y; v[6] = (int)u1.z; v[7] = (int)u1.w;
    af[t] = v;
  }
  // C-seeds h = -fn2/2 for this lane's C rows (16 broadcast dword loads)
  f32x4 h[4];
  #pragma unroll
  for (int t = 0; t < 4; ++t)
    #pragma unroll
    for (int i = 0; i < 4; ++i)
      h[t][i] = -0.5f * fn2[bN + r0 + t * 16 + q * 4 + i];

  float rowmax[4][4];
  #pragma unroll
  for (int t = 0; t < 4; ++t)
    #pragma unroll
    for (int i = 0; i < 4; ++i) rowmax[t][i] = -3.4e38f;

  // packed B fragment base for this wave's lane
  const unsigned char* pkw = pkB + (size_t)tile0 * TILE_B + lane * 16;
  const float*         gnb = gn2 + bN + slice * SLICE_W;

  auto loadB = [&](int mt, i32x8& bf, float& gv) {
    const unsigned char* base = pkw + (size_t)mt * TILE_B;
    uint4 u0 = *(const uint4*)base;
    uint4 u1 = *(const uint4*)(base + 1024);
    bf[0] = (int)u0.x; bf[1] = (int)u0.y; bf[2] = (int)u0.z; bf[3] = (int)u0.w;
    bf[4] = (int)u1.x; bf[5] = (int)u1.y; bf[6] = (int)u1.z; bf[7] = (int)u1.w;
    gv = gnb[mt * 16 + l15];
  };

  auto compute = [&](const i32x8& bf, float gv, int mt) {
    const float g2 = -0.5f * gv;
    float cm0, cm1, cm2, cm3;
    f32x4 aP, aQ;
    // sequential-t, 2-acc ping-pong: epilogue of t overlaps MFMA of t+1
    __builtin_amdgcn_s_setprio(1);
    aP = __builtin_amdgcn_mfma_scale_f32_16x16x128_f8f6f4(
        af[0], bf, h[0], 0, 0, 0, 0x7f7f7f7f, 0, 0x7f7f7f7f);
    aQ = __builtin_amdgcn_mfma_scale_f32_16x16x128_f8f6f4(
        af[1], bf, h[1], 0, 0, 0, 0x7f7f7f7f, 0, 0x7f7f7f7f);
    __builtin_amdgcn_s_setprio(0);
    #pragma unroll
    for (int i = 0; i < 4; ++i)
      rowmax[0][i] = fmaxf(rowmax[0][i], aP[i] + g2);
    cm0 = fmaxf(fmaxf(aP[0], aP[1]), fmaxf(aP[2], aP[3]));
    __builtin_amdgcn_s_setprio(1);
    aP = __builtin_amdgcn_mfma_scale_f32_16x16x128_f8f6f4(
        af[2], bf, h[2], 0, 0, 0, 0x7f7f7f7f, 0, 0x7f7f7f7f);
    __builtin_amdgcn_s_setprio(0);
    #pragma unroll
    for (int i = 0; i < 4; ++i)
      rowmax[1][i] = fmaxf(rowmax[1][i], aQ[i] + g2);
    cm1 = fmaxf(fmaxf(aQ[0], aQ[1]), fmaxf(aQ[2], aQ[3]));
    __builtin_amdgcn_s_setprio(1);
    aQ = __builtin_amdgcn_mfma_scale_f32_16x16x128_f8f6f4(
        af[3], bf, h[3], 0, 0, 0, 0x7f7f7f7f, 0, 0x7f7f7f7f);
    __builtin_amdgcn_s_setprio(0);
    #pragma unroll
    for (int i = 0; i < 4; ++i)
      rowmax[2][i] = fmaxf(rowmax[2][i], aP[i] + g2);
    cm2 = fmaxf(fmaxf(aP[0], aP[1]), fmaxf(aP[2], aP[3]));
    #pragma unroll
    for (int i = 0; i < 4; ++i)
      rowmax[3][i] = fmaxf(rowmax[3][i], aQ[i] + g2);
    cm3 = fmaxf(fmaxf(aQ[0], aQ[1]), fmaxf(aQ[2], aQ[3]));
    float cmax = fmaxf(fmaxf(cm0, cm1), fmaxf(cm2, cm3));
    // fire-and-forget LDS atomic (4-way same-address per col); gn2 deferred
    atomicMin(&cl[mt * 16 + l15], encf(-2.f * cmax));
  };

  // 2-deep B ping-pong
  i32x8 bA, bB;
  float gA, gB;
  loadB(0, bA, gA);
  for (int mt = 0; mt < ITERS; mt += 2) {
    loadB(mt + 1, bB, gB);
    compute(bA, gA, mt);
    loadB((mt + 2) & (ITERS - 1), bA, gA);
    compute(bB, gB, mt + 1);
  }

  // finalize row mins: reduce MAX over the 16 column-lanes, dis = -2*max
  #pragma unroll
  for (int t = 0; t < 4; ++t)
    #pragma unroll
    for (int i = 0; i < 4; ++i) {
      float v = rowmax[t][i];
      v = fmaxf(v, __shfl_xor(v, 1));
      v = fmaxf(v, __shfl_xor(v, 2));
      v = fmaxf(v, __shfl_xor(v, 4));
      v = fmaxf(v, __shfl_xor(v, 8));
      if (l15 == 0)
        atomicMin(&rowmin[bN + r0 + t * 16 + q * 4 + i], encf(-2.f * v));
    }

  // merge block col maxes into global: dis = decoded + gn2[col]
  __syncthreads();
  #pragma unroll
  for (int k = 0; k < SLICE_W / 256; ++k) {
    int c = threadIdx.x + k * 256;
    float d = decf(cl[c]) + gnb[c];
    atomicMin(&colmin[bN + slice * SLICE_W + c], encf(d));
  }
}

// ---- reduction stage 1: 128 blocks x 256 thr ----
__global__ void reduce1_kernel(const unsigned int* __restrict__ rowmin,
                               const unsigned int* __restrict__ colmin,
                               float* __restrict__ partial) {
  __shared__ float sbuf[4];
  int i = blockIdx.x * 256 + threadIdx.x;
  float s = decf(rowmin[i]) + decf(colmin[i]);
  #pragma unroll
  for (int o = 32; o >= 1; o >>= 1) s += __shfl_xor(s, o);
  if ((threadIdx.x & 63) == 0) sbuf[threadIdx.x >> 6] = s;
  __syncthreads();
  if (threadIdx.x == 0)
    partial[blockIdx.x] = sbuf[0] + sbuf[1] + sbuf[2] + sbuf[3];
}

// ---- reduction stage 2: 1 block, 64 thr ----
__global__ void reduce2_kernel(const float* __restrict__ partial,
                               float* __restrict__ out) {
  float s = partial[threadIdx.x] + partial[threadIdx.x + 64];
  #pragma unroll
  for (int o = 32; o >= 1; o >>= 1) s += __shfl_xor(s, o);
  if (threadIdx.x == 0) out[0] = s / (float)TOTAL_ROWS;
}

extern "C" void kernel_launch(void* const* d_in, const int* in_sizes, int n_in,
                              void* d_out, int out_size, void* d_ws, size_t ws_size,
                              hipStream_t stream) {
  (void)in_sizes; (void)n_in; (void)out_size; (void)ws_size;
  const float* f  = (const float*)d_in[0];
  const float* f_ = (const float*)d_in[1];

  char* ws = (char*)d_ws;
  unsigned char* pkB = (unsigned char*)ws;                         // 4 MiB packed fp8 f_
  unsigned char* pkA = (unsigned char*)(ws + 4u * 1024u * 1024u);  // 4 MiB packed fp8 f
  float* gn2 = (float*)(ws + 8u * 1024u * 1024u);                  // 128 KiB
  float* fn2 = gn2 + TOTAL_ROWS;                                   // 128 KiB
  unsigned int* rowmin = (unsigned int*)(fn2 + TOTAL_ROWS);        // 128 KiB
  unsigned int* colmin = rowmin + TOTAL_ROWS;                      // 128 KiB
  float* partial = (float*)(colmin + TOTAL_ROWS);                  // 512 B

  pack_kernel<<<2048, 256, 0, stream>>>(f_, pkB, gn2);
  pack_kernel<<<2048, 256, 0, stream>>>(f,  pkA, fn2);
  hipMemsetAsync(rowmin, 0xFF, (size_t)TOTAL_ROWS * 4, stream);
  hipMemsetAsync(colmin, 0xFF, (size_t)TOTAL_ROWS * 4, stream);
  chamfer_mfma_kernel<<<1024, 256, 0, stream>>>(pkA, pkB, fn2, gn2, rowmin, colmin);
  reduce1_kernel<<<128, 256, 0, stream>>>(rowmin, colmin, partial);
  reduce2_kernel<<<1, 64, 0, stream>>>(partial, (float*)d_out);
}

// Round 18
// 59.452 us; speedup vs baseline: 1.5925x; 1.0806x over previous
//
#include <hip/hip_runtime.h>

#define BATCH 4
#define NPTS 8192
#define DIM 128
#define TOTAL_ROWS (BATCH * NPTS)   // 32768
#define SLICES 8                    // m-slices per batch
#define SLICE_W 1024                // cols per slice
#define ITERS 64                    // 16-col tiles per slice
#define TILES_PER_B 512             // NPTS/16
#define TILE_B 2048                 // bytes per packed fp8 16-col tile

typedef __attribute__((ext_vector_type(8))) int   i32x8;
typedef __attribute__((ext_vector_type(4))) float f32x4;

// monotonic encoding of float for unsigned atomicMin (3 ops: ashr, or, xor)
__device__ __forceinline__ unsigned encf(float f) {
  unsigned b = __float_as_uint(f);
  return b ^ ((unsigned)((int)b >> 31) | 0x80000000u);
}
__device__ __forceinline__ float decf(unsigned u) {
  unsigned b = (u & 0x80000000u) ? (u ^ 0x80000000u) : ~u;
  return __uint_as_float(b);
}

// pack 8 floats -> 8 fp8(e4m3) bytes in 2 dwords
__device__ __forceinline__ void pk8(const float4& x, const float4& y,
                                    unsigned& lo, unsigned& hi) {
  lo = __builtin_amdgcn_cvt_pk_fp8_f32(x.x, x.y, 0, 0);
  lo = __builtin_amdgcn_cvt_pk_fp8_f32(x.z, x.w, lo, 1);
  hi = __builtin_amdgcn_cvt_pk_fp8_f32(y.x, y.y, 0, 0);
  hi = __builtin_amdgcn_cvt_pk_fp8_f32(y.z, y.w, hi, 1);
}

// ---- pack a point set into fp8 MFMA-fragment order + NEG-HALF row norms ----
// NEW layout: lane fl's 32 k-bytes are CONTIGUOUS at tile_base + fl*32
// (enables single i32x8 load with uniform base + lane*32 voffset)
__global__ void pack_kernel(const float* __restrict__ in,
                            unsigned char* __restrict__ pk,
                            float* __restrict__ n2h) {
  __shared__ float sred[16][17];
  int tl  = threadIdx.x;               // 0..255
  int fl  = tl >> 2;                   // fragment lane 0..63
  int p   = tl & 3;                    // 8-byte group within lane's 32
  int row = fl & 15, kch = fl >> 4;
  int tile = blockIdx.x;               // b*512 + mtg
  int b = tile >> 9, mtg = tile & 511;
  const float* src = in + (size_t)(b * NPTS + mtg * 16 + row) * DIM + kch * 32 + p * 8;
  float4 x = ((const float4*)src)[0], y = ((const float4*)src)[1];
  unsigned lo, hi;
  pk8(x, y, lo, hi);
  *(uint2*)(pk + (size_t)tile * TILE_B + fl * 32 + p * 8) = make_uint2(lo, hi);
  float s = 0.f;
  s = fmaf(x.x, x.x, s); s = fmaf(x.y, x.y, s);
  s = fmaf(x.z, x.z, s); s = fmaf(x.w, x.w, s);
  s = fmaf(y.x, y.x, s); s = fmaf(y.y, y.y, s);
  s = fmaf(y.z, y.z, s); s = fmaf(y.w, y.w, s);
  sred[row][kch * 4 + p] = s;
  __syncthreads();
  if (tl < 16) {
    float t = 0.f;
    #pragma unroll
    for (int j = 0; j < 16; ++j) t += sred[tl][j];
    n2h[tile * 16 + tl] = -0.5f * t;    // store -n2/2 (saves per-iter mul)
  }
}

// ---- main: per wave, 64 f-rows (packed fp8 A) x 1024-col slice ----
// fp8 K=128 MFMA, C-seeded with -fn2/2, 2-deep ping-pong, setprio,
// uniform-base + lane*32 addressing (SALU increments), 3-op encf.
__global__ __launch_bounds__(256, 4)
void chamfer_mfma_kernel(const unsigned char* __restrict__ pkA,
                         const unsigned char* __restrict__ pkB,
                         const float* __restrict__ fnh,
                         const float* __restrict__ gnh,
                         unsigned int* __restrict__ rowmin,
                         unsigned int* __restrict__ colmin) {
  const int lane = threadIdx.x & 63;
  const int l15  = lane & 15;
  const int q    = lane >> 4;                       // 0..3
  const int widx = threadIdx.x >> 6;                // 0..3
  const int loff = lane * 32;                       // per-lane byte offset

  // XCD-aware: 4 (b,slice) combos per XCD, 32 row-groups each
  const int bid   = blockIdx.x;                     // 0..1023
  const int combo = (bid & 7) * 4 + ((bid >> 3) & 3);  // 0..31
  const int b     = combo >> 3;
  const int slice = combo & 7;
  const int rgrp  = bid >> 5;                       // 0..31
  const int r0    = rgrp * 256 + widx * 64;
  const int bN    = b * NPTS;
  const int tile0 = b * TILES_PER_B + slice * ITERS;

  // block-level column-max accumulator of encf(-2*cmax); gn added at merge
  __shared__ unsigned cl[SLICE_W];
  #pragma unroll
  for (int k = 0; k < SLICE_W / 256; ++k)
    cl[threadIdx.x + k * 256] = 0xFFFFFFFFu;
  __syncthreads();

  // ---- A fragments from packed pkA (uniform base + loff) ----
  i32x8 af[4];
  const int atile0 = b * TILES_PER_B + (r0 >> 4);
  #pragma unroll
  for (int t = 0; t < 4; ++t) {
    const unsigned char* ub = pkA + (size_t)(atile0 + t) * TILE_B;
    af[t] = *(const i32x8*)(ub + loff);
  }
  // C-seeds h = -fn2/2 (pre-halved in fnh) for this lane's C rows
  f32x4 h[4];
  #pragma unroll
  for (int t = 0; t < 4; ++t)
    #pragma unroll
    for (int i = 0; i < 4; ++i)
      h[t][i] = fnh[bN + r0 + t * 16 + q * 4 + i];

  float rowmax[4][4];
  #pragma unroll
  for (int t = 0; t < 4; ++t)
    #pragma unroll
    for (int i = 0; i < 4; ++i) rowmax[t][i] = -3.4e38f;

  const unsigned char* pkw = pkB + (size_t)tile0 * TILE_B;  // uniform
  const float*         gnb = gnh + bN + slice * SLICE_W;

  auto loadB = [&](int mt, i32x8& bf, float& gv) {
    const unsigned char* ub = pkw + (size_t)mt * TILE_B;    // uniform + SALU
    bf = *(const i32x8*)(ub + loff);
    gv = gnb[mt * 16 + l15];                                // = -gn2/2
  };

  auto compute = [&](const i32x8& bf, float g2, int mt) {
    // acc = dot - fn2[r]/2 (C-operand seeded)
    f32x4 acc[4];
    __builtin_amdgcn_s_setprio(1);
    #pragma unroll
    for (int t = 0; t < 4; ++t)
      acc[t] = __builtin_amdgcn_mfma_scale_f32_16x16x128_f8f6f4(
          af[t], bf, h[t], 0, 0, 0, 0x7f7f7f7f, 0, 0x7f7f7f7f);
    __builtin_amdgcn_s_setprio(0);

    // row side: rowmax tracks max(acc + g2) = -dis/2  (g2 = -gn2/2, per lane)
    #pragma unroll
    for (int t = 0; t < 4; ++t)
      #pragma unroll
      for (int i = 0; i < 4; ++i)
        rowmax[t][i] = fmaxf(rowmax[t][i], acc[t][i] + g2);

    // col side: cmax over the 16 raw acc (max3-fused tree)
    float m0 = fmaxf(fmaxf(acc[0][0], acc[0][1]), acc[0][2]);
    float m1 = fmaxf(fmaxf(acc[0][3], acc[1][0]), acc[1][1]);
    float m2 = fmaxf(fmaxf(acc[1][2], acc[1][3]), acc[2][0]);
    float m3 = fmaxf(fmaxf(acc[2][1], acc[2][2]), acc[2][3]);
    float m4 = fmaxf(fmaxf(acc[3][0], acc[3][1]), acc[3][2]);
    float n0 = fmaxf(fmaxf(m0, m1), m2);
    float n1 = fmaxf(fmaxf(m3, m4), acc[3][3]);
    float cmax = fmaxf(n0, n1);
    // fire-and-forget LDS atomic (4-way same-address per col)
    atomicMin(&cl[mt * 16 + l15], encf(-2.f * cmax));
  };

  // 2-deep ping-pong
  i32x8 bA, bB;
  float gA, gB;
  loadB(0, bA, gA);
  for (int mt = 0; mt < ITERS; mt += 2) {
    loadB(mt + 1, bB, gB);
    compute(bA, gA, mt);
    loadB((mt + 2) & (ITERS - 1), bA, gA);
    compute(bB, gB, mt + 1);
  }

  // finalize row mins: reduce MAX over the 16 column-lanes, dis = -2*max
  #pragma unroll
  for (int t = 0; t < 4; ++t)
    #pragma unroll
    for (int i = 0; i < 4; ++i) {
      float v = rowmax[t][i];
      v = fmaxf(v, __shfl_xor(v, 1));
      v = fmaxf(v, __shfl_xor(v, 2));
      v = fmaxf(v, __shfl_xor(v, 4));
      v = fmaxf(v, __shfl_xor(v, 8));
      if (l15 == 0)
        atomicMin(&rowmin[bN + r0 + t * 16 + q * 4 + i], encf(-2.f * v));
    }

  // merge block col maxes: dis = decoded(-2*cmax) + gn2 = decoded - 2*gnh
  __syncthreads();
  #pragma unroll
  for (int k = 0; k < SLICE_W / 256; ++k) {
    int c = threadIdx.x + k * 256;
    float d = decf(cl[c]) - 2.f * gnb[c];
    atomicMin(&colmin[bN + slice * SLICE_W + c], encf(d));
  }
}

// ---- reduction stage 1: 128 blocks x 256 thr ----
__global__ void reduce1_kernel(const unsigned int* __restrict__ rowmin,
                               const unsigned int* __restrict__ colmin,
                               float* __restrict__ partial) {
  __shared__ float sbuf[4];
  int i = blockIdx.x * 256 + threadIdx.x;
  float s = decf(rowmin[i]) + decf(colmin[i]);
  #pragma unroll
  for (int o = 32; o >= 1; o >>= 1) s += __shfl_xor(s, o);
  if ((threadIdx.x & 63) == 0) sbuf[threadIdx.x >> 6] = s;
  __syncthreads();
  if (threadIdx.x == 0)
    partial[blockIdx.x] = sbuf[0] + sbuf[1] + sbuf[2] + sbuf[3];
}

// ---- reduction stage 2: 1 block, 64 thr ----
__global__ void reduce2_kernel(const float* __restrict__ partial,
                               float* __restrict__ out) {
  float s = partial[threadIdx.x] + partial[threadIdx.x + 64];
  #pragma unroll
  for (int o = 32; o >= 1; o >>= 1) s += __shfl_xor(s, o);
  if (threadIdx.x == 0) out[0] = s / (float)TOTAL_ROWS;
}

extern "C" void kernel_launch(void* const* d_in, const int* in_sizes, int n_in,
                              void* d_out, int out_size, void* d_ws, size_t ws_size,
                              hipStream_t stream) {
  (void)in_sizes; (void)n_in; (void)out_size; (void)ws_size;
  const float* f  = (const float*)d_in[0];
  const float* f_ = (const float*)d_in[1];

  char* ws = (char*)d_ws;
  unsigned char* pkB = (unsigned char*)ws;                         // 4 MiB packed fp8 f_
  unsigned char* pkA = (unsigned char*)(ws + 4u * 1024u * 1024u);  // 4 MiB packed fp8 f
  float* gnh = (float*)(ws + 8u * 1024u * 1024u);                  // 128 KiB (-gn2/2)
  float* fnh = gnh + TOTAL_ROWS;                                   // 128 KiB (-fn2/2)
  unsigned int* rowmin = (unsigned int*)(fnh + TOTAL_ROWS);        // 128 KiB
  unsigned int* colmin = rowmin + TOTAL_ROWS;                      // 128 KiB
  float* partial = (float*)(colmin + TOTAL_ROWS);                  // 512 B

  pack_kernel<<<2048, 256, 0, stream>>>(f_, pkB, gnh);
  pack_kernel<<<2048, 256, 0, stream>>>(f,  pkA, fnh);
  hipMemsetAsync(rowmin, 0xFF, (size_t)TOTAL_ROWS * 4, stream);
  hipMemsetAsync(colmin, 0xFF, (size_t)TOTAL_ROWS * 4, stream);
  chamfer_mfma_kernel<<<1024, 256, 0, stream>>>(pkA, pkB, fnh, gnh, rowmin, colmin);
  reduce1_kernel<<<128, 256, 0, stream>>>(rowmin, colmin, partial);
  reduce2_kernel<<<1, 64, 0, stream>>>(partial, (float*)d_out);
}